// Round 6
// baseline (212.185 us; speedup 1.0000x reference)
//
#include <hip/hip_runtime.h>
#include <hip/hip_bf16.h>

// GAT x2 (3 heads, E=2048, batch 0 only) + 2-layer GCN, log_softmax / leaky.
// Non-neighbor exp(-30) terms (~1e-13 vs rowsums ~O(1e3)) are dropped.
// adj is 0/1 float -> converted ONCE to a 512 KB bitmask (k0); all E x E
// passes consume bits (32x less memory traffic than float adj).
// NOTE: harness reset (268 MB ws poison fill + input restore, ~60 us) is
// included in dur_us and is outside our control.

// ---------------------------------------------------------------------------
// K0: bitmask build. bm[row][64] uint32 words; bit (j&31) of word j>>5.
__global__ __launch_bounds__(256) void k0_bitmask(
    const float* __restrict__ adj0, unsigned int* __restrict__ bm) {
  int lane = threadIdx.x & 63, w = threadIdx.x >> 6;
  int row = blockIdx.x * 4 + w;
  const float* arow = adj0 + (size_t)row * 2048;
#pragma unroll 4
  for (int it = 0; it < 32; ++it) {
    float v = arow[it * 64 + lane];
    unsigned long long mask = __ballot(v == 1.0f);
    if (lane == 0) bm[row * 64 + it * 2] = (unsigned int)mask;
    else if (lane == 32) bm[row * 64 + it * 2 + 1] = (unsigned int)(mask >> 32);
  }
}

// ---------------------------------------------------------------------------
// K1: per-node features. hcol[36][2048] (comp = gat*18 + head*6 + d),
// pack1/pack2 [18][2048]: rows 0..5 = e, 6..11 = exp(e), 12..17 = exp(0.2e)
__global__ __launch_bounds__(256) void k1_features(
    const float* __restrict__ node, const float* __restrict__ uv,
    const float* __restrict__ Wt1, const float* __restrict__ at1,
    const float* __restrict__ Wt2, const float* __restrict__ at2,
    float* __restrict__ hcol, float* __restrict__ pack1, float* __restrict__ pack2) {
  __shared__ float sW[192];
  __shared__ float sA[12];
  int b = blockIdx.x;
  int g = b / 24;
  int h = (b / 8) % 3;
  int e = (b % 8) * 256 + threadIdx.x;
  const float* W = (g ? Wt2 : Wt1) + h * 192;
  const float* A = (g ? at2 : at1) + h * 12;
  const float* x = (g ? uv : node) + e * 32;
  if (threadIdx.x < 192) sW[threadIdx.x] = W[threadIdx.x];
  if (threadIdx.x < 12) sA[threadIdx.x] = A[threadIdx.x];
  __syncthreads();
  float xv[32];
#pragma unroll
  for (int i = 0; i < 32; ++i) xv[i] = x[i];
  float hv[6];
#pragma unroll
  for (int d = 0; d < 6; ++d) hv[d] = 0.f;
#pragma unroll
  for (int i = 0; i < 32; ++i)
#pragma unroll
    for (int d = 0; d < 6; ++d) hv[d] += xv[i] * sW[i * 6 + d];
  float e1 = 0.f, e2 = 0.f;
#pragma unroll
  for (int d = 0; d < 6; ++d) {
    e1 += hv[d] * sA[d];
    e2 += hv[d] * sA[6 + d];
  }
  int c = g * 3 + h;
#pragma unroll
  for (int d = 0; d < 6; ++d) hcol[(c * 6 + d) * 2048 + e] = hv[d];
  pack1[c * 2048 + e] = e1;
  pack1[(6 + c) * 2048 + e] = __expf(e1);
  pack1[(12 + c) * 2048 + e] = __expf(0.2f * e1);
  pack2[c * 2048 + e] = e2;
  pack2[(6 + c) * 2048 + e] = __expf(e2);
  pack2[(12 + c) * 2048 + e] = __expf(0.2f * e2);
}

// ---------------------------------------------------------------------------
// K2: invrs[c][i] = 1 / sum_j w(i,j,c), w = bit * (pos? p1*p2 : q1*q2).
// Block 384 (wave = comp c), 8 rows per block, lanes sweep j 4-at-a-time.
__global__ __launch_bounds__(384) void k2_rowsum(
    const unsigned int* __restrict__ bm, const float* __restrict__ pack1,
    const float* __restrict__ pack2, float* __restrict__ invrs) {
  int tid = threadIdx.x;
  int c = tid >> 6, lane = tid & 63;
  int i0 = blockIdx.x * 8;
  const float4* p2_4 = (const float4*)pack2;
  float e1r[8], p1r[8], q1r[8], sum[8];
#pragma unroll
  for (int r = 0; r < 8; ++r) {
    e1r[r] = pack1[c * 2048 + i0 + r];
    p1r[r] = pack1[(6 + c) * 2048 + i0 + r];
    q1r[r] = pack1[(12 + c) * 2048 + i0 + r];
    sum[r] = 0.f;
  }
  int sh = (lane & 7) * 4;
#pragma unroll
  for (int it = 0; it < 8; ++it) {
    int j4 = it * 64 + lane;  // float4 index; covers j = 4*j4 .. +3
    float4 e2 = p2_4[c * 512 + j4];
    float4 p2 = p2_4[(6 + c) * 512 + j4];
    float4 q2 = p2_4[(12 + c) * 512 + j4];
    int wbase = it * 8 + (lane >> 3);
    float abx, aby, abz, abw;
#pragma unroll
    for (int r = 0; r < 8; ++r) {
      unsigned int wd = bm[(i0 + r) * 64 + wbase] >> sh;
      { float e = e1r[r] + e2.x; bool p = e > 0.f;
        abx = (p ? p1r[r] : q1r[r]) * (p ? p2.x : q2.x); }
      { float e = e1r[r] + e2.y; bool p = e > 0.f;
        aby = (p ? p1r[r] : q1r[r]) * (p ? p2.y : q2.y); }
      { float e = e1r[r] + e2.z; bool p = e > 0.f;
        abz = (p ? p1r[r] : q1r[r]) * (p ? p2.z : q2.z); }
      { float e = e1r[r] + e2.w; bool p = e > 0.f;
        abw = (p ? p1r[r] : q1r[r]) * (p ? p2.w : q2.w); }
      float s = ((wd & 1u) ? abx : 0.f) + ((wd & 2u) ? aby : 0.f) +
                ((wd & 4u) ? abz : 0.f) + ((wd & 8u) ? abw : 0.f);
      sum[r] += s;
    }
  }
#pragma unroll
  for (int r = 0; r < 8; ++r) {
#pragma unroll
    for (int off = 32; off > 0; off >>= 1) sum[r] += __shfl_down(sum[r], off);
  }
  if (lane == 0) {
#pragma unroll
    for (int r = 0; r < 8; ++r) invrs[c * 2048 + i0 + r] = 1.0f / sum[r];
  }
}

// ---------------------------------------------------------------------------
// K3: hp[k][j] += sum_i w(i,j,c) * (h[i,k]*invrs[c][i]).
// Block 384 (wave = comp c). Each thread handles TWO j (jA, jA+64) so the
// wave-uniform LDS reads (pk, h) amortize. Grid (16 j-tiles of 128, 32
// i-splits of 64). Atomic merge into pre-zeroed hp.
__global__ __launch_bounds__(384) void k3_hprime(
    const unsigned int* __restrict__ bm, const float* __restrict__ hcol,
    const float* __restrict__ pack1, const float* __restrict__ pack2,
    const float* __restrict__ invrs, float* __restrict__ hp) {
  __shared__ float4 sPack[6 * 64];       // e1, p1, q1, 0 per (c, ii)
  __shared__ float sHS[6 * 64 * 8];      // scaled h, 6 used + 2 pad
  __shared__ unsigned int sM[64 * 4];    // mask words for 64 i x 128 j
  float4* sHS4 = (float4*)sHS;
  int tid = threadIdx.x;
  int c6 = tid >> 6, jl = tid & 63;
  int j0 = blockIdx.x * 128;
  int i0 = blockIdx.y * 64;
  int jA = j0 + jl, jB = jA + 64;
  float e2A = pack2[c6 * 2048 + jA];
  float p2A = pack2[(6 + c6) * 2048 + jA];
  float q2A = pack2[(12 + c6) * 2048 + jA];
  float e2B = pack2[c6 * 2048 + jB];
  float p2B = pack2[(6 + c6) * 2048 + jB];
  float q2B = pack2[(12 + c6) * 2048 + jB];
  // stage
  {
    int cc = c6, ii = jl;
    float e1 = pack1[cc * 2048 + i0 + ii];
    float p1 = pack1[(6 + cc) * 2048 + i0 + ii];
    float q1 = pack1[(12 + cc) * 2048 + i0 + ii];
    sPack[cc * 64 + ii] = make_float4(e1, p1, q1, 0.f);
    float iv = invrs[cc * 2048 + i0 + ii];
#pragma unroll
    for (int d = 0; d < 6; ++d)
      sHS[(cc * 64 + ii) * 8 + d] = hcol[(cc * 6 + d) * 2048 + i0 + ii] * iv;
    sHS[(cc * 64 + ii) * 8 + 6] = 0.f;
    sHS[(cc * 64 + ii) * 8 + 7] = 0.f;
  }
  if (tid < 256) sM[tid] = bm[(size_t)(i0 + (tid >> 2)) * 64 + (j0 >> 5) + (tid & 3)];
  __syncthreads();
  float aA0 = 0.f, aA1 = 0.f, aA2 = 0.f, aA3 = 0.f, aA4 = 0.f, aA5 = 0.f;
  float aB0 = 0.f, aB1 = 0.f, aB2 = 0.f, aB3 = 0.f, aB4 = 0.f, aB5 = 0.f;
  int hi = jl >> 5;          // 0 or 1
  int shj = jl & 31;
#pragma unroll 8
  for (int ii = 0; ii < 64; ++ii) {
    float4 pk = sPack[c6 * 64 + ii];
    float4 h0 = sHS4[(c6 * 64 + ii) * 2];
    float4 h1 = sHS4[(c6 * 64 + ii) * 2 + 1];
    unsigned int wdA = sM[ii * 4 + hi];
    unsigned int wdB = sM[ii * 4 + 2 + hi];
    {
      float e = pk.x + e2A; bool p = e > 0.f;
      float ab = (p ? pk.y : pk.z) * (p ? p2A : q2A);
      float wgt = ((wdA >> shj) & 1u) ? ab : 0.f;
      aA0 += wgt * h0.x; aA1 += wgt * h0.y; aA2 += wgt * h0.z;
      aA3 += wgt * h0.w; aA4 += wgt * h1.x; aA5 += wgt * h1.y;
    }
    {
      float e = pk.x + e2B; bool p = e > 0.f;
      float ab = (p ? pk.y : pk.z) * (p ? p2B : q2B);
      float wgt = ((wdB >> shj) & 1u) ? ab : 0.f;
      aB0 += wgt * h0.x; aB1 += wgt * h0.y; aB2 += wgt * h0.z;
      aB3 += wgt * h0.w; aB4 += wgt * h1.x; aB5 += wgt * h1.y;
    }
  }
  int kb = c6 * 6;
  atomicAdd(&hp[(kb + 0) * 2048 + jA], aA0);
  atomicAdd(&hp[(kb + 1) * 2048 + jA], aA1);
  atomicAdd(&hp[(kb + 2) * 2048 + jA], aA2);
  atomicAdd(&hp[(kb + 3) * 2048 + jA], aA3);
  atomicAdd(&hp[(kb + 4) * 2048 + jA], aA4);
  atomicAdd(&hp[(kb + 5) * 2048 + jA], aA5);
  atomicAdd(&hp[(kb + 0) * 2048 + jB], aB0);
  atomicAdd(&hp[(kb + 1) * 2048 + jB], aB1);
  atomicAdd(&hp[(kb + 2) * 2048 + jB], aB2);
  atomicAdd(&hp[(kb + 3) * 2048 + jB], aB3);
  atomicAdd(&hp[(kb + 4) * 2048 + jB], aB4);
  atomicAdd(&hp[(kb + 5) * 2048 + jB], aB5);
}

// ---------------------------------------------------------------------------
// K4: elu(hp) -> T[j][32] = {hcY@Wg1, hcO@Wo1}. 32 j per block, grid 64.
__global__ __launch_bounds__(256) void k4_T(
    const float* __restrict__ hp, const float* __restrict__ Wg1,
    const float* __restrict__ Wo1, float* __restrict__ T) {
  __shared__ float sHP[32 * 37];
  __shared__ float sWg[288], sWo[288];
  int tid = threadIdx.x;
  int j0 = blockIdx.x * 32;
  for (int idx = tid; idx < 288; idx += 256) {
    sWg[idx] = Wg1[idx];
    sWo[idx] = Wo1[idx];
  }
  for (int idx = tid; idx < 1152; idx += 256) {
    int r = idx >> 5, jl = idx & 31;
    sHP[jl * 37 + r] = hp[r * 2048 + j0 + jl];
  }
  __syncthreads();
  int jl = tid & 31, wq = tid >> 5;   // wq: gat(2) x colgroup(4)
  int gat = wq >> 2;
  int c0 = (wq & 3) * 4;
  const float* Wp = gat ? sWo : sWg;
  float acc[4];
#pragma unroll
  for (int t = 0; t < 4; ++t) acc[t] = 0.f;
#pragma unroll
  for (int r = 0; r < 18; ++r) {
    float x = sHP[jl * 37 + gat * 18 + r];
    float hc = x > 0.f ? x : __expf(x) - 1.f;
#pragma unroll
    for (int t = 0; t < 4; ++t) acc[t] += hc * Wp[r * 16 + c0 + t];
  }
#pragma unroll
  for (int t = 0; t < 4; ++t) T[(j0 + jl) * 32 + gat * 16 + c0 + t] = acc[t];
}

// ---------------------------------------------------------------------------
// K5: Craw[r][c] += sum_k bit(r,k) * T[k][c]. LDS: T k-tile (16 KB) + mask
// words. Thread = (rowpair, 4-col group): 2 rows/thread halves LDS b128
// traffic. Grid (32 row-tiles of 64, 16 k-splits of 128). Atomic merge.
__global__ __launch_bounds__(256) void k5_gcn1(
    const unsigned int* __restrict__ bm, const float* __restrict__ T,
    float* __restrict__ Craw) {
  __shared__ unsigned int sM[64 * 4];
  __shared__ float4 sT4[128 * 8];
  const float4* T4 = (const float4*)T;
  int tid = threadIdx.x;
  int rl = tid & 31, cg = tid >> 5;
  int i0 = blockIdx.x * 64;
  int k0 = blockIdx.y * 128;
  if (tid < 256) sM[tid] = bm[(size_t)(i0 + (tid >> 2)) * 64 + (k0 >> 5) + (tid & 3)];
  for (int idx = tid; idx < 1024; idx += 256) sT4[idx] = T4[k0 * 8 + idx];
  __syncthreads();
  float a0x = 0.f, a0y = 0.f, a0z = 0.f, a0w = 0.f;
  float a1x = 0.f, a1y = 0.f, a1z = 0.f, a1w = 0.f;
#pragma unroll
  for (int wi = 0; wi < 4; ++wi) {
    unsigned int wA = sM[rl * 4 + wi];
    unsigned int wB = sM[(rl + 32) * 4 + wi];
#pragma unroll 16
    for (int kb = 0; kb < 32; ++kb) {
      float4 t = sT4[(wi * 32 + kb) * 8 + cg];
      float mA = (float)((wA >> kb) & 1u);
      float mB = (float)((wB >> kb) & 1u);
      a0x += mA * t.x; a0y += mA * t.y; a0z += mA * t.z; a0w += mA * t.w;
      a1x += mB * t.x; a1y += mB * t.y; a1z += mB * t.z; a1w += mB * t.w;
    }
  }
  float* d0 = &Craw[(i0 + rl) * 32 + cg * 4];
  atomicAdd(d0 + 0, a0x); atomicAdd(d0 + 1, a0y);
  atomicAdd(d0 + 2, a0z); atomicAdd(d0 + 3, a0w);
  float* d1 = &Craw[(i0 + rl + 32) * 32 + cg * 4];
  atomicAdd(d1 + 0, a1x); atomicAdd(d1 + 1, a1y);
  atomicAdd(d1 + 2, a1z); atomicAdd(d1 + 3, a1w);
}

// ---------------------------------------------------------------------------
// K6: T2[j][4] = {relu(Craw_Y+bg1)@Wg2, relu(Craw_O+bo1)@Wo2}.
__global__ __launch_bounds__(256) void k6_T2(
    const float* __restrict__ Craw, const float* __restrict__ bg1,
    const float* __restrict__ Wg2, const float* __restrict__ bo1,
    const float* __restrict__ Wo2, float* __restrict__ T2) {
  int tid = threadIdx.x;
  int wave = tid >> 6, lane = tid & 63;
  int j = blockIdx.x * 8 + wave * 2 + (lane >> 5);
  int cl = lane & 31;
  int gat = cl >> 4, cc = cl & 15;
  float x = Craw[j * 32 + cl];
  x += gat ? bo1[cc] : bg1[cc];
  x = x > 0.f ? x : 0.f;
  float wa = gat ? Wo2[cc * 2 + 0] : Wg2[cc * 2 + 0];
  float wb = gat ? Wo2[cc * 2 + 1] : Wg2[cc * 2 + 1];
  float pa = x * wa, pb = x * wb;
#pragma unroll
  for (int m = 8; m > 0; m >>= 1) {
    pa += __shfl_xor(pa, m);
    pb += __shfl_xor(pb, m);
  }
  if (cc == 0) {
    T2[j * 4 + gat * 2 + 0] = pa;
    T2[j * 4 + gat * 2 + 1] = pb;
  }
}

// ---------------------------------------------------------------------------
// K7: final out = a0 @ T2 (+bias), log_softmax(axis=1) + leaky(0.01).
// Wave per row, lanes sweep k; mask words broadcast, T2 float4 L2-hot.
__global__ __launch_bounds__(256) void k7_final(
    const unsigned int* __restrict__ bm, const float* __restrict__ T2,
    const float* __restrict__ bg2, const float* __restrict__ bo2,
    float* __restrict__ out) {
  int tid = threadIdx.x;
  int lane = tid & 63, w = tid >> 6;
  int r = blockIdx.x * 4 + w;
  const float4* T24 = (const float4*)T2;
  float4 acc = make_float4(0.f, 0.f, 0.f, 0.f);
  int sh = lane & 31;
#pragma unroll 8
  for (int it = 0; it < 32; ++it) {
    int k = it * 64 + lane;
    unsigned int wd = bm[r * 64 + it * 2 + (lane >> 5)];
    float m = (float)((wd >> sh) & 1u);
    float4 t = T24[k];
    acc.x += m * t.x;
    acc.y += m * t.y;
    acc.z += m * t.z;
    acc.w += m * t.w;
  }
#pragma unroll
  for (int off = 32; off > 0; off >>= 1) {
    acc.x += __shfl_down(acc.x, off);
    acc.y += __shfl_down(acc.y, off);
    acc.z += __shfl_down(acc.z, off);
    acc.w += __shfl_down(acc.w, off);
  }
  if (lane == 0) {
    float y0 = acc.x + bg2[0], y1 = acc.y + bg2[1];
    float m = fmaxf(y0, y1);
    float ls = m + logf(__expf(y0 - m) + __expf(y1 - m));
    out[r * 2 + 0] = y0 - ls;
    out[r * 2 + 1] = y1 - ls;
    float o0 = acc.z + bo2[0], o1 = acc.w + bo2[1];
    out[4096 + r * 2 + 0] = o0 > 0.f ? o0 : 0.01f * o0;
    out[4096 + r * 2 + 1] = o1 > 0.f ? o1 : 0.01f * o1;
  }
}

extern "C" void kernel_launch(void* const* d_in, const int* in_sizes, int n_in,
                              void* d_out, int out_size, void* d_ws, size_t ws_size,
                              hipStream_t stream) {
  const float* node = (const float*)d_in[0];
  const float* uv = (const float*)d_in[1];
  const float* adj = (const float*)d_in[2];  // batch 0 = first 2048*2048
  const float* Wt1 = (const float*)d_in[3];
  const float* at1 = (const float*)d_in[4];
  const float* Wt2 = (const float*)d_in[5];
  const float* at2 = (const float*)d_in[6];
  const float* Wg1 = (const float*)d_in[7];
  const float* bg1 = (const float*)d_in[8];
  const float* Wg2 = (const float*)d_in[9];
  const float* bg2 = (const float*)d_in[10];
  const float* Wo1 = (const float*)d_in[11];
  const float* bo1 = (const float*)d_in[12];
  const float* Wo2 = (const float*)d_in[13];
  const float* bo2 = (const float*)d_in[14];
  float* ws = (float*)d_ws;
  float* hcol = ws;                          // 73728
  float* pack1 = ws + 73728;                 // 36864
  float* pack2 = ws + 110592;                // 36864
  float* invrs = ws + 147456;                // 12288
  float* T = ws + 159744;                    // 65536
  float* T2 = ws + 225280;                   // 8192
  float* hp = ws + 233472;                   // 73728 (zeroed)
  float* Craw = ws + 307200;                 // 65536 (zeroed)
  unsigned int* bm = (unsigned int*)(ws + 372736);  // 131072 u32 = 512 KB
  float* out = (float*)d_out;

  hipMemsetAsync(hp, 0, (73728 + 65536) * sizeof(float), stream);
  k0_bitmask<<<512, 256, 0, stream>>>(adj, bm);
  k1_features<<<48, 256, 0, stream>>>(node, uv, Wt1, at1, Wt2, at2, hcol, pack1, pack2);
  k2_rowsum<<<256, 384, 0, stream>>>(bm, pack1, pack2, invrs);
  k3_hprime<<<dim3(16, 32), 384, 0, stream>>>(bm, hcol, pack1, pack2, invrs, hp);
  k4_T<<<64, 256, 0, stream>>>(hp, Wg1, Wo1, T);
  k5_gcn1<<<dim3(32, 16), 256, 0, stream>>>(bm, T, Craw);
  k6_T2<<<256, 256, 0, stream>>>(Craw, bg1, Wg2, bo1, Wo2, T2);
  k7_final<<<512, 256, 0, stream>>>(bm, T2, bg2, bo2, out);
}

// Round 7
// 183.649 us; speedup vs baseline: 1.1554x; 1.1554x over previous
//
#include <hip/hip_runtime.h>
#include <hip/hip_bf16.h>

// GAT x2 (3 heads, E=2048, batch 0 only) + 2-layer GCN, log_softmax / leaky.
// Non-neighbor exp(-30) terms (~1e-13 vs rowsums ~O(1e3)) are dropped.
// adj -> 512 KB bitmask (k0); all E x E passes consume bits.
// R7: NO ATOMICS. Device-scope f32 atomicAdd = uncached 16 B HBM RMW
// (R6 evidence: k5 WRITE_SIZE == n_atomics*16B, dur invariant ~45us).
// Split-K now writes plain cached partial buffers, merged inline in the
// consumers (k4, k6) which have adequate grids.

// ---------------------------------------------------------------------------
// K0: bitmask build. bm[row][64] uint32 words; bit (j&31) of word j>>5.
__global__ __launch_bounds__(256) void k0_bitmask(
    const float* __restrict__ adj0, unsigned int* __restrict__ bm) {
  int lane = threadIdx.x & 63, w = threadIdx.x >> 6;
  int row = blockIdx.x * 4 + w;
  const float* arow = adj0 + (size_t)row * 2048;
#pragma unroll 4
  for (int it = 0; it < 32; ++it) {
    float v = arow[it * 64 + lane];
    unsigned long long mask = __ballot(v == 1.0f);
    if (lane == 0) bm[row * 64 + it * 2] = (unsigned int)mask;
    else if (lane == 32) bm[row * 64 + it * 2 + 1] = (unsigned int)(mask >> 32);
  }
}

// ---------------------------------------------------------------------------
// K1: per-node features. hcol[36][2048] (comp = gat*18 + head*6 + d),
// pack1/pack2 [18][2048]: rows 0..5 = e, 6..11 = exp(e), 12..17 = exp(0.2e)
__global__ __launch_bounds__(256) void k1_features(
    const float* __restrict__ node, const float* __restrict__ uv,
    const float* __restrict__ Wt1, const float* __restrict__ at1,
    const float* __restrict__ Wt2, const float* __restrict__ at2,
    float* __restrict__ hcol, float* __restrict__ pack1, float* __restrict__ pack2) {
  __shared__ float sW[192];
  __shared__ float sA[12];
  int b = blockIdx.x;
  int g = b / 24;
  int h = (b / 8) % 3;
  int e = (b % 8) * 256 + threadIdx.x;
  const float* W = (g ? Wt2 : Wt1) + h * 192;
  const float* A = (g ? at2 : at1) + h * 12;
  const float* x = (g ? uv : node) + e * 32;
  if (threadIdx.x < 192) sW[threadIdx.x] = W[threadIdx.x];
  if (threadIdx.x < 12) sA[threadIdx.x] = A[threadIdx.x];
  __syncthreads();
  float xv[32];
#pragma unroll
  for (int i = 0; i < 32; ++i) xv[i] = x[i];
  float hv[6];
#pragma unroll
  for (int d = 0; d < 6; ++d) hv[d] = 0.f;
#pragma unroll
  for (int i = 0; i < 32; ++i)
#pragma unroll
    for (int d = 0; d < 6; ++d) hv[d] += xv[i] * sW[i * 6 + d];
  float e1 = 0.f, e2 = 0.f;
#pragma unroll
  for (int d = 0; d < 6; ++d) {
    e1 += hv[d] * sA[d];
    e2 += hv[d] * sA[6 + d];
  }
  int c = g * 3 + h;
#pragma unroll
  for (int d = 0; d < 6; ++d) hcol[(c * 6 + d) * 2048 + e] = hv[d];
  pack1[c * 2048 + e] = e1;
  pack1[(6 + c) * 2048 + e] = __expf(e1);
  pack1[(12 + c) * 2048 + e] = __expf(0.2f * e1);
  pack2[c * 2048 + e] = e2;
  pack2[(6 + c) * 2048 + e] = __expf(e2);
  pack2[(12 + c) * 2048 + e] = __expf(0.2f * e2);
}

// ---------------------------------------------------------------------------
// K2: invrs[c][i] = 1 / sum_j w(i,j,c), w = bit * (pos? p1*p2 : q1*q2).
// Block 384 (wave = comp c), 8 rows per block, lanes sweep j 4-at-a-time.
__global__ __launch_bounds__(384) void k2_rowsum(
    const unsigned int* __restrict__ bm, const float* __restrict__ pack1,
    const float* __restrict__ pack2, float* __restrict__ invrs) {
  int tid = threadIdx.x;
  int c = tid >> 6, lane = tid & 63;
  int i0 = blockIdx.x * 8;
  const float4* p2_4 = (const float4*)pack2;
  float e1r[8], p1r[8], q1r[8], sum[8];
#pragma unroll
  for (int r = 0; r < 8; ++r) {
    e1r[r] = pack1[c * 2048 + i0 + r];
    p1r[r] = pack1[(6 + c) * 2048 + i0 + r];
    q1r[r] = pack1[(12 + c) * 2048 + i0 + r];
    sum[r] = 0.f;
  }
  int sh = (lane & 7) * 4;
#pragma unroll
  for (int it = 0; it < 8; ++it) {
    int j4 = it * 64 + lane;  // float4 index; covers j = 4*j4 .. +3
    float4 e2 = p2_4[c * 512 + j4];
    float4 p2 = p2_4[(6 + c) * 512 + j4];
    float4 q2 = p2_4[(12 + c) * 512 + j4];
    int wbase = it * 8 + (lane >> 3);
    float abx, aby, abz, abw;
#pragma unroll
    for (int r = 0; r < 8; ++r) {
      unsigned int wd = bm[(i0 + r) * 64 + wbase] >> sh;
      { float e = e1r[r] + e2.x; bool p = e > 0.f;
        abx = (p ? p1r[r] : q1r[r]) * (p ? p2.x : q2.x); }
      { float e = e1r[r] + e2.y; bool p = e > 0.f;
        aby = (p ? p1r[r] : q1r[r]) * (p ? p2.y : q2.y); }
      { float e = e1r[r] + e2.z; bool p = e > 0.f;
        abz = (p ? p1r[r] : q1r[r]) * (p ? p2.z : q2.z); }
      { float e = e1r[r] + e2.w; bool p = e > 0.f;
        abw = (p ? p1r[r] : q1r[r]) * (p ? p2.w : q2.w); }
      float s = ((wd & 1u) ? abx : 0.f) + ((wd & 2u) ? aby : 0.f) +
                ((wd & 4u) ? abz : 0.f) + ((wd & 8u) ? abw : 0.f);
      sum[r] += s;
    }
  }
#pragma unroll
  for (int r = 0; r < 8; ++r) {
#pragma unroll
    for (int off = 32; off > 0; off >>= 1) sum[r] += __shfl_down(sum[r], off);
  }
  if (lane == 0) {
#pragma unroll
    for (int r = 0; r < 8; ++r) invrs[c * 2048 + i0 + r] = 1.0f / sum[r];
  }
}

// ---------------------------------------------------------------------------
// K3: hp_part[s][k][j] = sum_{i in split s} w(i,j,c) * (h[i,k]*invrs[c][i]).
// Block 384 (wave = comp c), 2 j per thread. Grid (16 j-tiles of 128,
// 16 i-splits of 128; 2 staged 64-i rounds). Plain stores (no atomics).
__global__ __launch_bounds__(384) void k3_hprime(
    const unsigned int* __restrict__ bm, const float* __restrict__ hcol,
    const float* __restrict__ pack1, const float* __restrict__ pack2,
    const float* __restrict__ invrs, float* __restrict__ hp_part) {
  __shared__ float4 sPack[6 * 64];       // e1, p1, q1, 0 per (c, ii)
  __shared__ float sHS[6 * 64 * 8];      // scaled h, 6 used + 2 pad
  __shared__ unsigned int sM[64 * 4];    // mask words for 64 i x 128 j
  float4* sHS4 = (float4*)sHS;
  int tid = threadIdx.x;
  int c6 = tid >> 6, jl = tid & 63;
  int j0 = blockIdx.x * 128;
  int jA = j0 + jl, jB = jA + 64;
  float e2A = pack2[c6 * 2048 + jA];
  float p2A = pack2[(6 + c6) * 2048 + jA];
  float q2A = pack2[(12 + c6) * 2048 + jA];
  float e2B = pack2[c6 * 2048 + jB];
  float p2B = pack2[(6 + c6) * 2048 + jB];
  float q2B = pack2[(12 + c6) * 2048 + jB];
  float aA0 = 0.f, aA1 = 0.f, aA2 = 0.f, aA3 = 0.f, aA4 = 0.f, aA5 = 0.f;
  float aB0 = 0.f, aB1 = 0.f, aB2 = 0.f, aB3 = 0.f, aB4 = 0.f, aB5 = 0.f;
  int hi = jl >> 5;
  int shj = jl & 31;
  int ibeg = blockIdx.y * 128;
  for (int i0 = ibeg; i0 < ibeg + 128; i0 += 64) {
    __syncthreads();
    {
      int cc = c6, ii = jl;
      float e1 = pack1[cc * 2048 + i0 + ii];
      float p1 = pack1[(6 + cc) * 2048 + i0 + ii];
      float q1 = pack1[(12 + cc) * 2048 + i0 + ii];
      sPack[cc * 64 + ii] = make_float4(e1, p1, q1, 0.f);
      float iv = invrs[cc * 2048 + i0 + ii];
#pragma unroll
      for (int d = 0; d < 6; ++d)
        sHS[(cc * 64 + ii) * 8 + d] = hcol[(cc * 6 + d) * 2048 + i0 + ii] * iv;
      sHS[(cc * 64 + ii) * 8 + 6] = 0.f;
      sHS[(cc * 64 + ii) * 8 + 7] = 0.f;
    }
    if (tid < 256) sM[tid] = bm[(size_t)(i0 + (tid >> 2)) * 64 + (j0 >> 5) + (tid & 3)];
    __syncthreads();
#pragma unroll 8
    for (int ii = 0; ii < 64; ++ii) {
      float4 pk = sPack[c6 * 64 + ii];
      float4 h0 = sHS4[(c6 * 64 + ii) * 2];
      float4 h1 = sHS4[(c6 * 64 + ii) * 2 + 1];
      unsigned int wdA = sM[ii * 4 + hi];
      unsigned int wdB = sM[ii * 4 + 2 + hi];
      {
        float e = pk.x + e2A; bool p = e > 0.f;
        float ab = (p ? pk.y : pk.z) * (p ? p2A : q2A);
        float wgt = ((wdA >> shj) & 1u) ? ab : 0.f;
        aA0 += wgt * h0.x; aA1 += wgt * h0.y; aA2 += wgt * h0.z;
        aA3 += wgt * h0.w; aA4 += wgt * h1.x; aA5 += wgt * h1.y;
      }
      {
        float e = pk.x + e2B; bool p = e > 0.f;
        float ab = (p ? pk.y : pk.z) * (p ? p2B : q2B);
        float wgt = ((wdB >> shj) & 1u) ? ab : 0.f;
        aB0 += wgt * h0.x; aB1 += wgt * h0.y; aB2 += wgt * h0.z;
        aB3 += wgt * h0.w; aB4 += wgt * h1.x; aB5 += wgt * h1.y;
      }
    }
  }
  float* hp = hp_part + (size_t)blockIdx.y * 73728;
  int kb = c6 * 6;
  hp[(kb + 0) * 2048 + jA] = aA0;
  hp[(kb + 1) * 2048 + jA] = aA1;
  hp[(kb + 2) * 2048 + jA] = aA2;
  hp[(kb + 3) * 2048 + jA] = aA3;
  hp[(kb + 4) * 2048 + jA] = aA4;
  hp[(kb + 5) * 2048 + jA] = aA5;
  hp[(kb + 0) * 2048 + jB] = aB0;
  hp[(kb + 1) * 2048 + jB] = aB1;
  hp[(kb + 2) * 2048 + jB] = aB2;
  hp[(kb + 3) * 2048 + jB] = aB3;
  hp[(kb + 4) * 2048 + jB] = aB4;
  hp[(kb + 5) * 2048 + jB] = aB5;
}

// ---------------------------------------------------------------------------
// K4: merge 16 hp partials -> elu -> T[j][32] = {hcY@Wg1, hcO@Wo1}.
// 16 j per block, grid 128.
__global__ __launch_bounds__(256) void k4_T(
    const float* __restrict__ hp_part, const float* __restrict__ Wg1,
    const float* __restrict__ Wo1, float* __restrict__ T) {
  __shared__ float sHP[16 * 37];
  __shared__ float sWg[288], sWo[288];
  int tid = threadIdx.x;
  int j0 = blockIdx.x * 16;
  for (int idx = tid; idx < 288; idx += 256) {
    sWg[idx] = Wg1[idx];
    sWo[idx] = Wo1[idx];
  }
  for (int idx = tid; idx < 576; idx += 256) {
    int r = idx >> 4, jl = idx & 15;
    float s = 0.f;
#pragma unroll
    for (int sp = 0; sp < 16; ++sp)
      s += hp_part[(size_t)sp * 73728 + r * 2048 + j0 + jl];
    sHP[jl * 37 + r] = s;
  }
  __syncthreads();
  int jl = tid & 15, wq = tid >> 4;  // 16 slots: gat(2) x colpair(8)
  int gat = wq >> 3;
  int c0 = (wq & 7) * 2;
  const float* Wp = gat ? sWo : sWg;
  float a0 = 0.f, a1 = 0.f;
#pragma unroll
  for (int r = 0; r < 18; ++r) {
    float x = sHP[jl * 37 + gat * 18 + r];
    float hc = x > 0.f ? x : __expf(x) - 1.f;
    a0 += hc * Wp[r * 16 + c0];
    a1 += hc * Wp[r * 16 + c0 + 1];
  }
  T[(j0 + jl) * 32 + gat * 16 + c0] = a0;
  T[(j0 + jl) * 32 + gat * 16 + c0 + 1] = a1;
}

// ---------------------------------------------------------------------------
// K5: Craw_part[s][r][c] = sum_{k in split s} bit(r,k) * T[k][c].
// Same compute as R6; epilogue = plain float4 stores (no atomics).
// Grid (32 row-tiles of 64, 16 k-splits of 128).
__global__ __launch_bounds__(256) void k5_gcn1(
    const unsigned int* __restrict__ bm, const float* __restrict__ T,
    float* __restrict__ Craw_part) {
  __shared__ unsigned int sM[64 * 4];
  __shared__ float4 sT4[128 * 8];
  const float4* T4 = (const float4*)T;
  int tid = threadIdx.x;
  int rl = tid & 31, cg = tid >> 5;
  int i0 = blockIdx.x * 64;
  int k0 = blockIdx.y * 128;
  if (tid < 256) sM[tid] = bm[(size_t)(i0 + (tid >> 2)) * 64 + (k0 >> 5) + (tid & 3)];
  for (int idx = tid; idx < 1024; idx += 256) sT4[idx] = T4[k0 * 8 + idx];
  __syncthreads();
  float a0x = 0.f, a0y = 0.f, a0z = 0.f, a0w = 0.f;
  float a1x = 0.f, a1y = 0.f, a1z = 0.f, a1w = 0.f;
#pragma unroll
  for (int wi = 0; wi < 4; ++wi) {
    unsigned int wA = sM[rl * 4 + wi];
    unsigned int wB = sM[(rl + 32) * 4 + wi];
#pragma unroll 16
    for (int kb = 0; kb < 32; ++kb) {
      float4 t = sT4[(wi * 32 + kb) * 8 + cg];
      float mA = (float)((wA >> kb) & 1u);
      float mB = (float)((wB >> kb) & 1u);
      a0x += mA * t.x; a0y += mA * t.y; a0z += mA * t.z; a0w += mA * t.w;
      a1x += mB * t.x; a1y += mB * t.y; a1z += mB * t.z; a1w += mB * t.w;
    }
  }
  float* base = Craw_part + (size_t)blockIdx.y * 65536;
  *(float4*)&base[(i0 + rl) * 32 + cg * 4] = make_float4(a0x, a0y, a0z, a0w);
  *(float4*)&base[(i0 + rl + 32) * 32 + cg * 4] = make_float4(a1x, a1y, a1z, a1w);
}

// ---------------------------------------------------------------------------
// K6: merge 16 Craw partials, +bias, relu, @Wg2/@Wo2 -> T2[j][4].
__global__ __launch_bounds__(256) void k6_T2(
    const float* __restrict__ Craw_part, const float* __restrict__ bg1,
    const float* __restrict__ Wg2, const float* __restrict__ bo1,
    const float* __restrict__ Wo2, float* __restrict__ T2) {
  int tid = threadIdx.x;
  int wave = tid >> 6, lane = tid & 63;
  int j = blockIdx.x * 8 + wave * 2 + (lane >> 5);
  int cl = lane & 31;
  int gat = cl >> 4, cc = cl & 15;
  float x = 0.f;
#pragma unroll
  for (int sp = 0; sp < 16; ++sp) x += Craw_part[(size_t)sp * 65536 + j * 32 + cl];
  x += gat ? bo1[cc] : bg1[cc];
  x = x > 0.f ? x : 0.f;
  float wa = gat ? Wo2[cc * 2 + 0] : Wg2[cc * 2 + 0];
  float wb = gat ? Wo2[cc * 2 + 1] : Wg2[cc * 2 + 1];
  float pa = x * wa, pb = x * wb;
#pragma unroll
  for (int m = 8; m > 0; m >>= 1) {
    pa += __shfl_xor(pa, m);
    pb += __shfl_xor(pb, m);
  }
  if (cc == 0) {
    T2[j * 4 + gat * 2 + 0] = pa;
    T2[j * 4 + gat * 2 + 1] = pb;
  }
}

// ---------------------------------------------------------------------------
// K7: final out = a0 @ T2 (+bias), log_softmax(axis=1) + leaky(0.01).
// Wave per row, lanes sweep k; mask words broadcast, T2 float4 L2-hot.
__global__ __launch_bounds__(256) void k7_final(
    const unsigned int* __restrict__ bm, const float* __restrict__ T2,
    const float* __restrict__ bg2, const float* __restrict__ bo2,
    float* __restrict__ out) {
  int tid = threadIdx.x;
  int lane = tid & 63, w = tid >> 6;
  int r = blockIdx.x * 4 + w;
  const float4* T24 = (const float4*)T2;
  float4 acc = make_float4(0.f, 0.f, 0.f, 0.f);
  int sh = lane & 31;
#pragma unroll 8
  for (int it = 0; it < 32; ++it) {
    int k = it * 64 + lane;
    unsigned int wd = bm[r * 64 + it * 2 + (lane >> 5)];
    float m = (float)((wd >> sh) & 1u);
    float4 t = T24[k];
    acc.x += m * t.x;
    acc.y += m * t.y;
    acc.z += m * t.z;
    acc.w += m * t.w;
  }
#pragma unroll
  for (int off = 32; off > 0; off >>= 1) {
    acc.x += __shfl_down(acc.x, off);
    acc.y += __shfl_down(acc.y, off);
    acc.z += __shfl_down(acc.z, off);
    acc.w += __shfl_down(acc.w, off);
  }
  if (lane == 0) {
    float y0 = acc.x + bg2[0], y1 = acc.y + bg2[1];
    float m = fmaxf(y0, y1);
    float ls = m + logf(__expf(y0 - m) + __expf(y1 - m));
    out[r * 2 + 0] = y0 - ls;
    out[r * 2 + 1] = y1 - ls;
    float o0 = acc.z + bo2[0], o1 = acc.w + bo2[1];
    out[4096 + r * 2 + 0] = o0 > 0.f ? o0 : 0.01f * o0;
    out[4096 + r * 2 + 1] = o1 > 0.f ? o1 : 0.01f * o1;
  }
}

extern "C" void kernel_launch(void* const* d_in, const int* in_sizes, int n_in,
                              void* d_out, int out_size, void* d_ws, size_t ws_size,
                              hipStream_t stream) {
  const float* node = (const float*)d_in[0];
  const float* uv = (const float*)d_in[1];
  const float* adj = (const float*)d_in[2];  // batch 0 = first 2048*2048
  const float* Wt1 = (const float*)d_in[3];
  const float* at1 = (const float*)d_in[4];
  const float* Wt2 = (const float*)d_in[5];
  const float* at2 = (const float*)d_in[6];
  const float* Wg1 = (const float*)d_in[7];
  const float* bg1 = (const float*)d_in[8];
  const float* Wg2 = (const float*)d_in[9];
  const float* bg2 = (const float*)d_in[10];
  const float* Wo1 = (const float*)d_in[11];
  const float* bo1 = (const float*)d_in[12];
  const float* Wo2 = (const float*)d_in[13];
  const float* bo2 = (const float*)d_in[14];
  float* ws = (float*)d_ws;
  float* hcol = ws;                          // 73728
  float* pack1 = ws + 73728;                 // 36864
  float* pack2 = ws + 110592;                // 36864
  float* invrs = ws + 147456;                // 12288
  float* T = ws + 159744;                    // 65536
  float* T2 = ws + 225280;                   // 8192
  unsigned int* bm = (unsigned int*)(ws + 233472);  // 131072 u32 = 512 KB
  float* hp_part = ws + 364544;              // 16 * 73728 = 1179648
  float* Craw_part = ws + 1544192;           // 16 * 65536 = 1048576
  float* out = (float*)d_out;

  k0_bitmask<<<512, 256, 0, stream>>>(adj, bm);
  k1_features<<<48, 256, 0, stream>>>(node, uv, Wt1, at1, Wt2, at2, hcol, pack1, pack2);
  k2_rowsum<<<256, 384, 0, stream>>>(bm, pack1, pack2, invrs);
  k3_hprime<<<dim3(16, 16), 384, 0, stream>>>(bm, hcol, pack1, pack2, invrs, hp_part);
  k4_T<<<128, 256, 0, stream>>>(hp_part, Wg1, Wo1, T);
  k5_gcn1<<<dim3(32, 16), 256, 0, stream>>>(bm, T, Craw_part);
  k6_T2<<<256, 256, 0, stream>>>(Craw_part, bg1, Wg2, bo1, Wo2, T2);
  k7_final<<<512, 256, 0, stream>>>(bm, T2, bg2, bo2, out);
}